// Round 5
// baseline (502.061 us; speedup 1.0000x reference)
//
#include <hip/hip_runtime.h>

// ---------------------------------------------------------------------------
// Cascade MLP, MI355X. fp16 hi/lo split GEMMs on MFMA (3 passes, fp32 accum).
// k-OCTET fragment mapping: lane (l15,g) holds k in [8g, 8g+8) for BOTH A and
// B operands. Weight/h rows store [hi-plane][lo-plane]: one fragment == one
// ds_read_b128. Fused kernel; h lives in LDS throughout.
// Round-5 change: 64-row tiles -> LDS 74.75 KB -> 2 blocks/CU (2 waves/SIMD).
// Rationale: round-4 showed the gap is intra-CU latency exposure at 1
// wave/SIMD lockstep; occupancy doubling overlaps phase-2 (LDS/MFMA) with the
// sibling block's phase-1 (HBM) and fills barrier/latency stalls.
// ---------------------------------------------------------------------------

typedef __fp16 h2  __attribute__((ext_vector_type(2)));
typedef __fp16 h8v __attribute__((ext_vector_type(8)));
typedef float  f4v __attribute__((ext_vector_type(4)));

#define CHUNK 20480   // W chunk stride (18432 used: 128 rows x 144 B), 5x16B stage
#define WROW  144     // weight row: [hi 64B][lo 64B][pad 16B]; 36 dwords ≡ 4 mod 32
#define HROW  528     // h row: [hi 256B][lo 256B][pad 16B]; 132 dwords ≡ 4 mod 32
#define WOCH  12288   // head chunk stride (8448 used: 16 rows x 528 B), 3x16B stage
#define TROWS 64      // rows per block tile

static constexpr unsigned OFF_W1  = 0;                       // 96 chunks
static constexpr unsigned OFF_WH  = 96u * CHUNK;             // 56 chunks
static constexpr unsigned OFF_WO  = OFF_WH + 56u * CHUNK;    // 3 head chunks
static constexpr unsigned OFF_BIN = OFF_WO + 3u * WOCH;      // 128 f32
static constexpr unsigned OFF_BH  = OFF_BIN + 512;           // 14 x 128 f32
static constexpr unsigned OFF_BO  = OFF_BH + 14u * 512;      // 3 x 16 f32

__device__ __forceinline__ unsigned bc2(h2 v) { return __builtin_bit_cast(unsigned, v); }

__device__ __forceinline__ f4v ntld4(const float* p) {
  return __builtin_nontemporal_load((const f4v*)p);
}

__device__ __forceinline__ void lds_cp16(const char* g, char* l) {
  __builtin_amdgcn_global_load_lds(
      (const __attribute__((address_space(1))) void*)g,
      (__attribute__((address_space(3))) void*)l, 16, 0, 0);
}

__device__ __forceinline__ void stage5(const char* g, char* l, int tid) {
#pragma unroll
  for (int i = 0; i < 5; ++i) lds_cp16(g + i * 4096 + tid * 16, l + i * 4096 + tid * 16);
}
__device__ __forceinline__ void stage3(const char* g, char* l, int tid) {
#pragma unroll
  for (int i = 0; i < 3; ++i) lds_cp16(g + i * 4096 + tid * 16, l + i * 4096 + tid * 16);
}

// 8 fp32 (two f4v) -> hi/lo h8v fragments
__device__ __forceinline__ void cvt8(f4v a, f4v b, h8v& hi, h8v& lo) {
  h2 h0 = __builtin_amdgcn_cvt_pkrtz(a[0], a[1]);
  h2 h1 = __builtin_amdgcn_cvt_pkrtz(a[2], a[3]);
  h2 h2_ = __builtin_amdgcn_cvt_pkrtz(b[0], b[1]);
  h2 h3 = __builtin_amdgcn_cvt_pkrtz(b[2], b[3]);
  h2 l0 = __builtin_amdgcn_cvt_pkrtz(a[0] - (float)h0[0], a[1] - (float)h0[1]);
  h2 l1 = __builtin_amdgcn_cvt_pkrtz(a[2] - (float)h1[0], a[3] - (float)h1[1]);
  h2 l2 = __builtin_amdgcn_cvt_pkrtz(b[0] - (float)h2_[0], b[1] - (float)h2_[1]);
  h2 l3 = __builtin_amdgcn_cvt_pkrtz(b[2] - (float)h3[0], b[3] - (float)h3[1]);
  hi = h8v{h0[0], h0[1], h1[0], h1[1], h2_[0], h2_[1], h3[0], h3[1]};
  lo = h8v{l0[0], l0[1], l1[0], l1[1], l2[0], l2[1], l3[0], l3[1]};
}

__device__ __forceinline__ void split_store(f4v v, char* hip, char* lop) {
  h2 a = __builtin_amdgcn_cvt_pkrtz(v[0], v[1]);
  h2 b = __builtin_amdgcn_cvt_pkrtz(v[2], v[3]);
  h2 c = __builtin_amdgcn_cvt_pkrtz(v[0] - (float)a[0], v[1] - (float)a[1]);
  h2 d = __builtin_amdgcn_cvt_pkrtz(v[2] - (float)b[0], v[3] - (float)b[1]);
  *(uint2*)hip = make_uint2(bc2(a), bc2(b));
  *(uint2*)lop = make_uint2(bc2(c), bc2(d));
}

__device__ __forceinline__ void split8w(const float* f, uint4& hi, uint4& lo) {
  h2 h0 = __builtin_amdgcn_cvt_pkrtz(f[0], f[1]);
  h2 h1 = __builtin_amdgcn_cvt_pkrtz(f[2], f[3]);
  h2 h2_ = __builtin_amdgcn_cvt_pkrtz(f[4], f[5]);
  h2 h3 = __builtin_amdgcn_cvt_pkrtz(f[6], f[7]);
  h2 l0 = __builtin_amdgcn_cvt_pkrtz(f[0] - (float)h0[0], f[1] - (float)h0[1]);
  h2 l1 = __builtin_amdgcn_cvt_pkrtz(f[2] - (float)h1[0], f[3] - (float)h1[1]);
  h2 l2 = __builtin_amdgcn_cvt_pkrtz(f[4] - (float)h2_[0], f[5] - (float)h2_[1]);
  h2 l3 = __builtin_amdgcn_cvt_pkrtz(f[6] - (float)h3[0], f[7] - (float)h3[1]);
  hi = make_uint4(bc2(h0), bc2(h1), bc2(h2_), bc2(h3));
  lo = make_uint4(bc2(l0), bc2(l1), bc2(l2), bc2(l3));
}

// items: L0-3 = 0..15, head0 = 16, L4-8 = 17..36, head1 = 37,
// L9-13 = 38..57, head2 = 58  (59 items)
__device__ __forceinline__ unsigned item_off(int it) {
  if (it == 16) return OFF_WO;
  if (it == 37) return OFF_WO + WOCH;
  if (it == 58) return OFF_WO + 2u * WOCH;
  int j = it - (it > 16 ? 1 : 0) - (it > 37 ? 1 : 0);
  return OFF_WH + (unsigned)j * CHUNK;
}
__device__ __forceinline__ bool is_head(int it) { return it == 16 || it == 37 || it == 58; }

// ---------------------------------------------------------------------------
// prep: split+pad weights/biases into ws images (unchanged from round 3)
// ---------------------------------------------------------------------------
__global__ __launch_bounds__(256) void prep_k(
    const float* __restrict__ w_in, const float* __restrict__ b_in,
    const float* __restrict__ w_hid, const float* __restrict__ b_hid,
    const float* __restrict__ w_out, const float* __restrict__ b_out,
    char* __restrict__ ws) {
  int idx = blockIdx.x * 256 + threadIdx.x;
  float f[8];
  uint4 hi, lo;
  if (idx < 49152) {  // W1: c(96) x q(4) x n(128); k = c*32 + q*8 + j
    int n = idx & 127, cq = idx >> 7, q = cq & 3, c = cq >> 2;
    int k0 = c * 32 + q * 8;
#pragma unroll
    for (int j = 0; j < 8; ++j) f[j] = (n < 100) ? w_in[(size_t)(k0 + j) * 100 + n] : 0.f;
    split8w(f, hi, lo);
    char* dst = ws + OFF_W1 + (size_t)c * CHUNK + n * WROW + q * 16;
    *(uint4*)dst = hi;
    *(uint4*)(dst + 64) = lo;
    return;
  }
  idx -= 49152;
  if (idx < 28672) {  // WH: ch(56 = L*4+s) x q(4) x n(128); k = s*32 + q*8 + j
    int n = idx & 127, cq = idx >> 7, q = cq & 3, ch = cq >> 2;
    int L = ch >> 2, s = ch & 3;
    int k0 = s * 32 + q * 8;
#pragma unroll
    for (int j = 0; j < 8; ++j) {
      int k = k0 + j;
      f[j] = (k < 100 && n < 100) ? w_hid[(size_t)L * 10000 + k * 100 + n] : 0.f;
    }
    split8w(f, hi, lo);
    char* dst = ws + OFF_WH + (size_t)ch * CHUNK + n * WROW + q * 16;
    *(uint4*)dst = hi;
    *(uint4*)(dst + 64) = lo;
    return;
  }
  idx -= 28672;
  if (idx < 768) {  // WO: st(3) x q(16) x l(16); rows are HROW, full 128-k planes
    int l = idx & 15, sq = idx >> 4, q = sq & 15, st = sq >> 4;
    int k0 = q * 8;
#pragma unroll
    for (int j = 0; j < 8; ++j) {
      int k = k0 + j;
      f[j] = (k < 100 && l < 10) ? w_out[(size_t)st * 1000 + k * 10 + l] : 0.f;
    }
    split8w(f, hi, lo);
    char* dst = ws + OFF_WO + (size_t)st * WOCH + l * HROW + q * 16;
    *(uint4*)dst = hi;
    *(uint4*)(dst + 256) = lo;
    return;
  }
  idx -= 768;
  if (idx < 128) { ((float*)(ws + OFF_BIN))[idx] = (idx < 100) ? b_in[idx] : 0.f; return; }
  idx -= 128;
  if (idx < 1792) {
    int L = idx >> 7, n = idx & 127;
    ((float*)(ws + OFF_BH))[idx] = (n < 100) ? b_hid[L * 100 + n] : 0.f;
    return;
  }
  idx -= 1792;
  if (idx < 48) {
    int st = idx >> 4, n = idx & 15;
    ((float*)(ws + OFF_BO))[idx] = (n < 10) ? b_out[st * 10 + n] : -1e30f;
    return;
  }
}

// ---------------------------------------------------------------------------
// fused 64-row-tile kernel, 2 blocks/CU
// ---------------------------------------------------------------------------
#define SMEM_BYTES (TROWS * HROW + 2 * CHUNK)  // 33792 + 40960 = 74752

__global__ __launch_bounds__(256, 2) void fused_k(const float* __restrict__ x,
                                                  char* __restrict__ ws,
                                                  float* __restrict__ out) {
  extern __shared__ __align__(16) char sm[];
  char* smh = sm;                  // h tile: 64 rows x HROW
  char* smw = sm + TROWS * HROW;   // 2 x CHUNK staging buffers

  const int tid = threadIdx.x;
  const int lane = tid & 63, wid = tid >> 6;
  const int mr = wid >> 1, nc = wid & 1;     // feature-half / row-half
  const int l15 = lane & 15, g = lane >> 4;
  const int tile = blockIdx.x;

  f4v z = {0.f, 0.f, 0.f, 0.f};

  // ================= phase 1: h = relu(x @ w_in + b_in) =================
  {
    const char* w1g = ws + OFF_W1;
    // lane rows: r(nf) = tile*64 + nc*32 + nf*16 + l15, nf = 0,1
    const float* xr0 = x + (size_t)(tile * TROWS + nc * 32 + l15) * 3072;
    const float* xr1 = xr0 + (size_t)16 * 3072;

    f4v xaP[4], xaQ[4];
    // prologue FIFO: c0(5), x0(4), x1(4)
    stage5(w1g, smw, tid);
    __builtin_amdgcn_sched_barrier(0);
    xaP[0] = ntld4(xr0 + g * 8); xaP[1] = ntld4(xr0 + g * 8 + 4);
    xaP[2] = ntld4(xr1 + g * 8); xaP[3] = ntld4(xr1 + g * 8 + 4);
    {
      const int o = 32 + g * 8;
      xaQ[0] = ntld4(xr0 + o); xaQ[1] = ntld4(xr0 + o + 4);
      xaQ[2] = ntld4(xr1 + o); xaQ[3] = ntld4(xr1 + o + 4);
    }
    __builtin_amdgcn_sched_barrier(0);

    f4v acc[4][2];
#pragma unroll
    for (int mf = 0; mf < 4; ++mf) { acc[mf][0] = z; acc[mf][1] = z; }

    const int abase = (mr * 64 + l15) * WROW + g * 16;

    // steady FIFO at step s wait: [x(s)4, c(s)5, x(s+1)4] -> vmcnt(4)
    auto step = [&](int s, f4v (&xa)[4]) {
      if (s == 95) asm volatile("s_waitcnt vmcnt(0)" ::: "memory");
      else         asm volatile("s_waitcnt vmcnt(4)" ::: "memory");
      __builtin_amdgcn_s_barrier();
      asm volatile("" ::: "memory");

      h8v bhi0, blo0, bhi1, blo1;
      cvt8(xa[0], xa[1], bhi0, blo0);
      cvt8(xa[2], xa[3], bhi1, blo1);
      // refill: c(s+1) first, then x(s+2) (FIFO accounting)
      if (s < 95) stage5(w1g + (size_t)(s + 1) * CHUNK, smw + ((s + 1) & 1) * CHUNK, tid);
      if (s < 94) {
        const int o = (s + 2) * 32 + g * 8;
        xa[0] = ntld4(xr0 + o); xa[1] = ntld4(xr0 + o + 4);
        xa[2] = ntld4(xr1 + o); xa[3] = ntld4(xr1 + o + 4);
      }
      __builtin_amdgcn_sched_barrier(0);

      const char* ab = smw + (s & 1) * CHUNK + abase;
#pragma unroll
      for (int mf = 0; mf < 4; ++mf) {
        h8v ahi = *(const h8v*)(ab + mf * (16 * WROW));
        h8v alo = *(const h8v*)(ab + mf * (16 * WROW) + 64);
        acc[mf][0] = __builtin_amdgcn_mfma_f32_16x16x32_f16(ahi, bhi0, acc[mf][0], 0, 0, 0);
        acc[mf][0] = __builtin_amdgcn_mfma_f32_16x16x32_f16(ahi, blo0, acc[mf][0], 0, 0, 0);
        acc[mf][0] = __builtin_amdgcn_mfma_f32_16x16x32_f16(alo, bhi0, acc[mf][0], 0, 0, 0);
        acc[mf][1] = __builtin_amdgcn_mfma_f32_16x16x32_f16(ahi, bhi1, acc[mf][1], 0, 0, 0);
        acc[mf][1] = __builtin_amdgcn_mfma_f32_16x16x32_f16(ahi, blo1, acc[mf][1], 0, 0, 0);
        acc[mf][1] = __builtin_amdgcn_mfma_f32_16x16x32_f16(alo, bhi1, acc[mf][1], 0, 0, 0);
      }
    };

#pragma unroll 1
    for (int s2 = 0; s2 < 96; s2 += 2) {
      step(s2, xaP);
      step(s2 + 1, xaQ);
    }

    // epilogue: pre-stage item 0, then bias+relu+split -> h rows in LDS
    stage5(ws + item_off(0), smw, tid);
    const float* binp = (const float*)(ws + OFF_BIN);
#pragma unroll
    for (int nf = 0; nf < 2; ++nf) {
      char* hrow = smh + (nc * 32 + nf * 16 + l15) * HROW;
#pragma unroll
      for (int mf = 0; mf < 4; ++mf) {
        f4v bi = *(const f4v*)(binp + mr * 64 + mf * 16 + g * 4);
        f4v v = acc[mf][nf] + bi;
        v[0] = fmaxf(v[0], 0.f); v[1] = fmaxf(v[1], 0.f);
        v[2] = fmaxf(v[2], 0.f); v[3] = fmaxf(v[3], 0.f);
        split_store(v, hrow + mr * 128 + mf * 32 + g * 8,
                    hrow + 256 + mr * 128 + mf * 32 + g * 8);
      }
    }
    __syncthreads();  // drains item-0 stage + h ds_writes
  }

  // ================= phase 2: cascade =================
  f4v acc[4][2] = {{z, z}, {z, z}, {z, z}, {z, z}};
  f4v o0[2], o1[2], o2[2];
  unsigned conf = 0;
  int item = 0;

  auto item_top = [&]() {
    __syncthreads();  // drains staged item(item) + fences LDS
    if (item + 1 < 59) {
      unsigned off = item_off(item + 1);
      char* buf = smw + ((item + 1) & 1) * CHUNK;
      if (is_head(item + 1)) stage3(ws + off, buf, tid);
      else                   stage5(ws + off, buf, tid);
    }
  };

  auto hidden = [&](int L) {
#pragma unroll
    for (int ss = 0; ss < 4; ++ss) {
      item_top();
      const char* wb = smw + (item & 1) * CHUNK + g * 16;
      const char* hb = smh + ss * 64 + g * 16;
      h8v bhi[2], blo[2];
#pragma unroll
      for (int nf = 0; nf < 2; ++nf) {
        const char* p = hb + (nc * 32 + nf * 16 + l15) * HROW;
        bhi[nf] = *(const h8v*)p;
        blo[nf] = *(const h8v*)(p + 256);
      }
#pragma unroll
      for (int mf = 0; mf < 4; ++mf) {
        const char* pa = wb + (mr * 64 + mf * 16 + l15) * WROW;
        h8v ahi = *(const h8v*)pa;
        h8v alo = *(const h8v*)(pa + 64);
#pragma unroll
        for (int nf = 0; nf < 2; ++nf) {
          acc[mf][nf] = __builtin_amdgcn_mfma_f32_16x16x32_f16(ahi, bhi[nf], acc[mf][nf], 0, 0, 0);
          acc[mf][nf] = __builtin_amdgcn_mfma_f32_16x16x32_f16(ahi, blo[nf], acc[mf][nf], 0, 0, 0);
          acc[mf][nf] = __builtin_amdgcn_mfma_f32_16x16x32_f16(alo, bhi[nf], acc[mf][nf], 0, 0, 0);
        }
      }
      ++item;
    }
    const float* bh = (const float*)(ws + OFF_BH) + L * 128 + mr * 64;
    __syncthreads();  // all reads of old h done
#pragma unroll
    for (int mf = 0; mf < 4; ++mf) {
      f4v bi = *(const f4v*)(bh + mf * 16 + g * 4);
#pragma unroll
      for (int nf = 0; nf < 2; ++nf) {
        f4v v = acc[mf][nf] + bi;
        v[0] = fmaxf(v[0], 0.f); v[1] = fmaxf(v[1], 0.f);
        v[2] = fmaxf(v[2], 0.f); v[3] = fmaxf(v[3], 0.f);
        char* hrow = smh + (nc * 32 + nf * 16 + l15) * HROW;
        split_store(v, hrow + mr * 128 + mf * 32 + g * 8,
                    hrow + 256 + mr * 128 + mf * 32 + g * 8);
        acc[mf][nf] = z;
      }
    }
    __syncthreads();  // new h visible
  };

  auto wstage = [&](f4v (&o)[2], int st, int shift) {
    item_top();
    const char* wb = smw + (item & 1) * CHUNK;
    if (mr == 0) {  // waves 0,1: wave-uniform branch
      f4v oa[2] = {z, z};
#pragma unroll
      for (int ss = 0; ss < 4; ++ss) {
        const char* pa = wb + l15 * HROW + ss * 64 + g * 16;
        h8v ahi = *(const h8v*)pa;
        h8v alo = *(const h8v*)(pa + 256);
#pragma unroll
        for (int nf = 0; nf < 2; ++nf) {
          const char* pb = smh + (nc * 32 + nf * 16 + l15) * HROW + ss * 64 + g * 16;
          h8v bhi = *(const h8v*)pb;
          h8v blo = *(const h8v*)(pb + 256);
          oa[nf] = __builtin_amdgcn_mfma_f32_16x16x32_f16(ahi, bhi, oa[nf], 0, 0, 0);
          oa[nf] = __builtin_amdgcn_mfma_f32_16x16x32_f16(ahi, blo, oa[nf], 0, 0, 0);
          oa[nf] = __builtin_amdgcn_mfma_f32_16x16x32_f16(alo, bhi, oa[nf], 0, 0, 0);
        }
      }
      f4v bi = *(const f4v*)((const float*)(ws + OFF_BO) + st * 16 + g * 4);
#pragma unroll
      for (int nf = 0; nf < 2; ++nf) {
        oa[nf] += bi;  // padded classes carry bias -1e30
        float m = fmaxf(fmaxf(oa[nf][0], oa[nf][1]), fmaxf(oa[nf][2], oa[nf][3]));
        m = fmaxf(m, __shfl_xor(m, 16, 64));
        m = fmaxf(m, __shfl_xor(m, 32, 64));
        if (m > 0.5f) conf |= 1u << (shift + nf);
        o[nf] = oa[nf];
      }
    }
    ++item;
  };

#pragma unroll 1
  for (int L = 0; L < 4; ++L) hidden(L);
  wstage(o0, 0, 0);
#pragma unroll 1
  for (int L = 4; L < 9; ++L) hidden(L);
  wstage(o1, 1, 2);
#pragma unroll 1
  for (int L = 9; L < 14; ++L) hidden(L);
  wstage(o2, 2, 4);

  if (mr == 0) {  // early-exit select + store (64 rows via nc, nf, l15)
#pragma unroll
    for (int nf = 0; nf < 2; ++nf) {
      bool c0 = (conf >> (0 + nf)) & 1u, c1 = (conf >> (2 + nf)) & 1u;
      f4v r;
#pragma unroll
      for (int j = 0; j < 4; ++j) r[j] = c0 ? o0[nf][j] : (c1 ? o1[nf][j] : o2[nf][j]);
      float* dp = out + (size_t)(tile * TROWS + nc * 32 + nf * 16 + l15) * 10;
      if (g == 0) {
        *(float2*)(dp) = make_float2(r[0], r[1]);
        *(float2*)(dp + 2) = make_float2(r[2], r[3]);
      } else if (g == 1) {
        *(float2*)(dp + 4) = make_float2(r[0], r[1]);
        *(float2*)(dp + 6) = make_float2(r[2], r[3]);
      } else if (g == 2) {
        *(float2*)(dp + 8) = make_float2(r[0], r[1]);
      }
    }
  }
}

// ---------------------------------------------------------------------------
extern "C" void kernel_launch(void* const* d_in, const int* in_sizes, int n_in,
                              void* d_out, int out_size, void* d_ws, size_t ws_size,
                              hipStream_t stream) {
  (void)in_sizes; (void)n_in; (void)out_size; (void)ws_size;
  const float* x     = (const float*)d_in[0];
  const float* w_in  = (const float*)d_in[1];
  const float* b_in  = (const float*)d_in[2];
  const float* w_hid = (const float*)d_in[3];
  const float* b_hid = (const float*)d_in[4];
  const float* w_out = (const float*)d_in[5];
  const float* b_out = (const float*)d_in[6];
  float* out = (float*)d_out;
  char* ws = (char*)d_ws;

  (void)hipFuncSetAttribute((const void*)fused_k,
                            hipFuncAttributeMaxDynamicSharedMemorySize, SMEM_BYTES);

  prep_k<<<315, 256, 0, stream>>>(w_in, b_in, w_hid, b_hid, w_out, b_out, ws);
  fused_k<<<1024, 256, SMEM_BYTES, stream>>>(x, ws, out);
}

// Round 6
// 377.308 us; speedup vs baseline: 1.3306x; 1.3306x over previous
//
#include <hip/hip_runtime.h>

// ---------------------------------------------------------------------------
// Cascade MLP, MI355X. fp16 hi/lo split GEMMs on MFMA (3 passes, fp32 accum).
// k-OCTET fragment mapping: lane (l15,g) holds k in [8g, 8g+8) for BOTH A and
// B operands. Weight/h rows store [hi-plane][lo-plane]: one fragment == one
// ds_read_b128. Fused kernel; h lives in LDS throughout. 128-row tiles,
// 512 blocks, 1 block/CU (round-5's 2-block attempt did not co-reside and
// doubled staging overhead -> reverted).
// Round-6 change: phase-2 item pipeline uses RAW s_barrier + counted
// vmcnt(10) (3 buffers, 2 items in flight). __syncthreads() was draining the
// prefetch every item (vmcnt(0) before s_barrier). All stages uniform 5x16B;
// dummy tail stages keep the FIFO accounting compile-time constant. Biases
// are DMA'd to LDS once so no global loads disturb the vmcnt FIFO.
// ---------------------------------------------------------------------------

typedef __fp16 h2  __attribute__((ext_vector_type(2)));
typedef __fp16 h8v __attribute__((ext_vector_type(8)));
typedef float  f4v __attribute__((ext_vector_type(4)));

#define CHUNK 20480   // W chunk stride (18432 used: 128 rows x 144 B), 5x16B stage
#define WROW  144     // weight row: [hi 64B][lo 64B][pad 16B]
#define HROW  528     // h row: [hi 256B][lo 256B][pad 16B]
#define WOCH  20480   // head chunk stride (8448 used: 16 rows x 528 B), 5x16B stage

static constexpr unsigned OFF_W1  = 0;                       // 96 chunks
static constexpr unsigned OFF_WH  = 96u * CHUNK;             // 1966080, 56 chunks
static constexpr unsigned OFF_WO  = OFF_WH + 56u * CHUNK;    // 3112960, 3 head chunks
static constexpr unsigned OFF_BIN = OFF_WO + 3u * WOCH;      // 3174400, 128 f32
static constexpr unsigned OFF_BH  = OFF_BIN + 512;           // 14 x 128 f32
static constexpr unsigned OFF_BO  = OFF_BH + 7168;           // 3 x 16 f32

// LDS layout
#define LDS_H    0          // 128 * 528 = 67584
#define LDS_W    67584      // 3 * CHUNK = 61440
#define LDS_B    129024     // 8192 (biases: BIN @0, BH @512, BO @7680)
#define SMEM_BYTES 137216

__device__ __forceinline__ unsigned bc2(h2 v) { return __builtin_bit_cast(unsigned, v); }

__device__ __forceinline__ f4v ntld4(const float* p) {
  return __builtin_nontemporal_load((const f4v*)p);
}

__device__ __forceinline__ void lds_cp16(const char* g, char* l) {
  __builtin_amdgcn_global_load_lds(
      (const __attribute__((address_space(1))) void*)g,
      (__attribute__((address_space(3))) void*)l, 16, 0, 0);
}

__device__ __forceinline__ void stage5(const char* g, char* l, int tid) {
#pragma unroll
  for (int i = 0; i < 5; ++i) lds_cp16(g + i * 4096 + tid * 16, l + i * 4096 + tid * 16);
}

// 8 fp32 (two f4v) -> hi/lo h8v fragments
__device__ __forceinline__ void cvt8(f4v a, f4v b, h8v& hi, h8v& lo) {
  h2 h0 = __builtin_amdgcn_cvt_pkrtz(a[0], a[1]);
  h2 h1 = __builtin_amdgcn_cvt_pkrtz(a[2], a[3]);
  h2 h2_ = __builtin_amdgcn_cvt_pkrtz(b[0], b[1]);
  h2 h3 = __builtin_amdgcn_cvt_pkrtz(b[2], b[3]);
  h2 l0 = __builtin_amdgcn_cvt_pkrtz(a[0] - (float)h0[0], a[1] - (float)h0[1]);
  h2 l1 = __builtin_amdgcn_cvt_pkrtz(a[2] - (float)h1[0], a[3] - (float)h1[1]);
  h2 l2 = __builtin_amdgcn_cvt_pkrtz(b[0] - (float)h2_[0], b[1] - (float)h2_[1]);
  h2 l3 = __builtin_amdgcn_cvt_pkrtz(b[2] - (float)h3[0], b[3] - (float)h3[1]);
  hi = h8v{h0[0], h0[1], h1[0], h1[1], h2_[0], h2_[1], h3[0], h3[1]};
  lo = h8v{l0[0], l0[1], l1[0], l1[1], l2[0], l2[1], l3[0], l3[1]};
}

__device__ __forceinline__ void split_store(f4v v, char* hip, char* lop) {
  h2 a = __builtin_amdgcn_cvt_pkrtz(v[0], v[1]);
  h2 b = __builtin_amdgcn_cvt_pkrtz(v[2], v[3]);
  h2 c = __builtin_amdgcn_cvt_pkrtz(v[0] - (float)a[0], v[1] - (float)a[1]);
  h2 d = __builtin_amdgcn_cvt_pkrtz(v[2] - (float)b[0], v[3] - (float)b[1]);
  *(uint2*)hip = make_uint2(bc2(a), bc2(b));
  *(uint2*)lop = make_uint2(bc2(c), bc2(d));
}

__device__ __forceinline__ void split8w(const float* f, uint4& hi, uint4& lo) {
  h2 h0 = __builtin_amdgcn_cvt_pkrtz(f[0], f[1]);
  h2 h1 = __builtin_amdgcn_cvt_pkrtz(f[2], f[3]);
  h2 h2_ = __builtin_amdgcn_cvt_pkrtz(f[4], f[5]);
  h2 h3 = __builtin_amdgcn_cvt_pkrtz(f[6], f[7]);
  h2 l0 = __builtin_amdgcn_cvt_pkrtz(f[0] - (float)h0[0], f[1] - (float)h0[1]);
  h2 l1 = __builtin_amdgcn_cvt_pkrtz(f[2] - (float)h1[0], f[3] - (float)h1[1]);
  h2 l2 = __builtin_amdgcn_cvt_pkrtz(f[4] - (float)h2_[0], f[5] - (float)h2_[1]);
  h2 l3 = __builtin_amdgcn_cvt_pkrtz(f[6] - (float)h3[0], f[7] - (float)h3[1]);
  hi = make_uint4(bc2(h0), bc2(h1), bc2(h2_), bc2(h3));
  lo = make_uint4(bc2(l0), bc2(l1), bc2(l2), bc2(l3));
}

// items: L0-3 = 0..15, head0 = 16, L4-8 = 17..36, head1 = 37,
// L9-13 = 38..57, head2 = 58  (59 items)
__device__ __forceinline__ unsigned item_off(int it) {
  if (it >= 58) return OFF_WO + 2u * WOCH;   // 58 and dummy tails
  if (it == 16) return OFF_WO;
  if (it == 37) return OFF_WO + WOCH;
  int j = it - (it > 16 ? 1 : 0) - (it > 37 ? 1 : 0);
  return OFF_WH + (unsigned)j * CHUNK;
}

// ---------------------------------------------------------------------------
// prep: split+pad weights/biases into ws images
// ---------------------------------------------------------------------------
__global__ __launch_bounds__(256) void prep_k(
    const float* __restrict__ w_in, const float* __restrict__ b_in,
    const float* __restrict__ w_hid, const float* __restrict__ b_hid,
    const float* __restrict__ w_out, const float* __restrict__ b_out,
    char* __restrict__ ws) {
  int idx = blockIdx.x * 256 + threadIdx.x;
  float f[8];
  uint4 hi, lo;
  if (idx < 49152) {  // W1: c(96) x q(4) x n(128); k = c*32 + q*8 + j
    int n = idx & 127, cq = idx >> 7, q = cq & 3, c = cq >> 2;
    int k0 = c * 32 + q * 8;
#pragma unroll
    for (int j = 0; j < 8; ++j) f[j] = (n < 100) ? w_in[(size_t)(k0 + j) * 100 + n] : 0.f;
    split8w(f, hi, lo);
    char* dst = ws + OFF_W1 + (size_t)c * CHUNK + n * WROW + q * 16;
    *(uint4*)dst = hi;
    *(uint4*)(dst + 64) = lo;
    return;
  }
  idx -= 49152;
  if (idx < 28672) {  // WH: ch(56 = L*4+s) x q(4) x n(128); k = s*32 + q*8 + j
    int n = idx & 127, cq = idx >> 7, q = cq & 3, ch = cq >> 2;
    int L = ch >> 2, s = ch & 3;
    int k0 = s * 32 + q * 8;
#pragma unroll
    for (int j = 0; j < 8; ++j) {
      int k = k0 + j;
      f[j] = (k < 100 && n < 100) ? w_hid[(size_t)L * 10000 + k * 100 + n] : 0.f;
    }
    split8w(f, hi, lo);
    char* dst = ws + OFF_WH + (size_t)ch * CHUNK + n * WROW + q * 16;
    *(uint4*)dst = hi;
    *(uint4*)(dst + 64) = lo;
    return;
  }
  idx -= 28672;
  if (idx < 768) {  // WO: st(3) x q(16) x l(16); rows are HROW, full 128-k planes
    int l = idx & 15, sq = idx >> 4, q = sq & 15, st = sq >> 4;
    int k0 = q * 8;
#pragma unroll
    for (int j = 0; j < 8; ++j) {
      int k = k0 + j;
      f[j] = (k < 100 && l < 10) ? w_out[(size_t)st * 1000 + k * 10 + l] : 0.f;
    }
    split8w(f, hi, lo);
    char* dst = ws + OFF_WO + (size_t)st * WOCH + l * HROW + q * 16;
    *(uint4*)dst = hi;
    *(uint4*)(dst + 256) = lo;
    return;
  }
  idx -= 768;
  if (idx < 128) { ((float*)(ws + OFF_BIN))[idx] = (idx < 100) ? b_in[idx] : 0.f; return; }
  idx -= 128;
  if (idx < 1792) {
    int L = idx >> 7, n = idx & 127;
    ((float*)(ws + OFF_BH))[idx] = (n < 100) ? b_hid[L * 100 + n] : 0.f;
    return;
  }
  idx -= 1792;
  if (idx < 48) {
    int st = idx >> 4, n = idx & 15;
    ((float*)(ws + OFF_BO))[idx] = (n < 10) ? b_out[st * 10 + n] : -1e30f;
    return;
  }
}

// ---------------------------------------------------------------------------
// fused kernel: 128-row tiles, 512 blocks, 1 block/CU
// ---------------------------------------------------------------------------
__global__ __launch_bounds__(256, 1) void fused_k(const float* __restrict__ x,
                                                  char* __restrict__ ws,
                                                  float* __restrict__ out) {
  extern __shared__ __align__(16) char sm[];
  char* smh = sm + LDS_H;
  char* smw = sm + LDS_W;
  char* smb = sm + LDS_B;

  const int tid = threadIdx.x;
  const int lane = tid & 63, wid = tid >> 6;
  const int l15 = lane & 15, g = lane >> 4;
  const int tile = blockIdx.x;

  f4v z = {0.f, 0.f, 0.f, 0.f};

  // ================= phase 1: h = relu(x @ w_in + b_in) =================
  {
    const char* w1g = ws + OFF_W1;
    // bias DMA (2 loads) -- issued first, drained by the first vmcnt(9)
    lds_cp16((const char*)ws + OFF_BIN + tid * 16, smb + tid * 16);
    lds_cp16((const char*)ws + OFF_BIN + 4096 + tid * 16, smb + 4096 + tid * 16);
    __builtin_amdgcn_sched_barrier(0);

    const float* xr0 = x + (size_t)(tile * 128 + wid * 32 + l15) * 3072;
    const float* xr1 = xr0 + (size_t)16 * 3072;

    f4v xaP[4], xaQ[4];
    stage5(w1g, smw, tid);                       // c0
    __builtin_amdgcn_sched_barrier(0);
    xaP[0] = ntld4(xr0 + g * 8); xaP[1] = ntld4(xr0 + g * 8 + 4);
    xaP[2] = ntld4(xr1 + g * 8); xaP[3] = ntld4(xr1 + g * 8 + 4);
    __builtin_amdgcn_sched_barrier(0);
    stage5(w1g + CHUNK, smw + CHUNK, tid);       // c1
    __builtin_amdgcn_sched_barrier(0);
    {
      const int o = 32 + g * 8;
      xaQ[0] = ntld4(xr0 + o); xaQ[1] = ntld4(xr0 + o + 4);
      xaQ[2] = ntld4(xr1 + o); xaQ[3] = ntld4(xr1 + o + 4);
    }
    __builtin_amdgcn_sched_barrier(0);

    f4v acc[8][2];
#pragma unroll
    for (int mf = 0; mf < 8; ++mf) { acc[mf][0] = z; acc[mf][1] = z; }

    const int abase = l15 * WROW + g * 16;

    auto step = [&](int s, f4v (&xa)[4]) {
      if (s == 95) asm volatile("s_waitcnt vmcnt(0)" ::: "memory");
      else         asm volatile("s_waitcnt vmcnt(9)" ::: "memory");
      __builtin_amdgcn_s_barrier();
      asm volatile("" ::: "memory");

      h8v bhi0, blo0, bhi1, blo1;
      cvt8(xa[0], xa[1], bhi0, blo0);
      cvt8(xa[2], xa[3], bhi1, blo1);
      if (s + 2 < 96) {
        stage5(w1g + (size_t)(s + 2) * CHUNK, smw + ((s + 2) % 3) * CHUNK, tid);
        const int o = (s + 2) * 32 + g * 8;
        xa[0] = ntld4(xr0 + o); xa[1] = ntld4(xr0 + o + 4);
        xa[2] = ntld4(xr1 + o); xa[3] = ntld4(xr1 + o + 4);
      }
      __builtin_amdgcn_sched_barrier(0);

      const char* ab = smw + (s % 3) * CHUNK + abase;
#pragma unroll
      for (int mf = 0; mf < 8; ++mf) {
        h8v ahi = *(const h8v*)(ab + mf * (16 * WROW));
        h8v alo = *(const h8v*)(ab + mf * (16 * WROW) + 64);
        acc[mf][0] = __builtin_amdgcn_mfma_f32_16x16x32_f16(ahi, bhi0, acc[mf][0], 0, 0, 0);
        acc[mf][0] = __builtin_amdgcn_mfma_f32_16x16x32_f16(ahi, blo0, acc[mf][0], 0, 0, 0);
        acc[mf][0] = __builtin_amdgcn_mfma_f32_16x16x32_f16(alo, bhi0, acc[mf][0], 0, 0, 0);
        acc[mf][1] = __builtin_amdgcn_mfma_f32_16x16x32_f16(ahi, bhi1, acc[mf][1], 0, 0, 0);
        acc[mf][1] = __builtin_amdgcn_mfma_f32_16x16x32_f16(ahi, blo1, acc[mf][1], 0, 0, 0);
        acc[mf][1] = __builtin_amdgcn_mfma_f32_16x16x32_f16(alo, bhi1, acc[mf][1], 0, 0, 0);
      }
    };

#pragma unroll 1
    for (int s2 = 0; s2 < 96; s2 += 2) {
      step(s2, xaP);
      step(s2 + 1, xaQ);
    }

    // epilogue: pre-stage phase-2 items 0,1 (stay in flight!), bias+relu+split
    stage5(ws + item_off(0), smw, tid);
    stage5(ws + item_off(1), smw + CHUNK, tid);
    __builtin_amdgcn_sched_barrier(0);
    const float* binp = (const float*)smb;
#pragma unroll
    for (int nf = 0; nf < 2; ++nf) {
      char* hrow = smh + (wid * 32 + nf * 16 + l15) * HROW;
#pragma unroll
      for (int mf = 0; mf < 8; ++mf) {
        f4v bi = *(const f4v*)(binp + mf * 16 + g * 4);
        f4v v = acc[mf][nf] + bi;
        v[0] = fmaxf(v[0], 0.f); v[1] = fmaxf(v[1], 0.f);
        v[2] = fmaxf(v[2], 0.f); v[3] = fmaxf(v[3], 0.f);
        split_store(v, hrow + mf * 32 + g * 8, hrow + 256 + mf * 32 + g * 8);
      }
    }
    asm volatile("s_waitcnt lgkmcnt(0)" ::: "memory");
    __builtin_amdgcn_s_barrier();
    asm volatile("" ::: "memory");
  }

  // ================= phase 2: cascade (counted-vmcnt item pipeline) ========
  const int mr = wid >> 1, nc = wid & 1;
  f4v acc[4][4] = {{z, z, z, z}, {z, z, z, z}, {z, z, z, z}, {z, z, z, z}};
  f4v o0[4], o1[4], o2[4];
  unsigned conf = 0;
  int item = 0;
  int cur = 0, nb = 2;  // current buf = item%3; next stage buf = (item+2)%3

  // top of each item: issue stage(item+2), then wait so that stage(item) is
  // complete (<=10 outstanding = items item+1, item+2). Dummy stages keep the
  // count uniform at the tail.
  auto item_top = [&]() {
    stage5(ws + item_off(item + 2), smw + nb * CHUNK, tid);
    nb = (nb == 2) ? 0 : nb + 1;
    asm volatile("s_waitcnt vmcnt(10)" ::: "memory");
    asm volatile("" ::: "memory");
  };
  auto item_bot = [&]() {
    __builtin_amdgcn_s_barrier();
    asm volatile("" ::: "memory");
    cur = (cur == 2) ? 0 : cur + 1;
    ++item;
  };

  auto hidden = [&](int L) {
#pragma unroll
    for (int ss = 0; ss < 4; ++ss) {
      item_top();
      const char* wb = smw + cur * CHUNK + g * 16;
      const char* hb = smh + ss * 64 + g * 16;
      h8v bhi[4], blo[4];
#pragma unroll
      for (int nf = 0; nf < 4; ++nf) {
        const char* p = hb + (nc * 64 + nf * 16 + l15) * HROW;
        bhi[nf] = *(const h8v*)p;
        blo[nf] = *(const h8v*)(p + 256);
      }
#pragma unroll
      for (int mf = 0; mf < 4; ++mf) {
        const char* pa = wb + (mr * 64 + mf * 16 + l15) * WROW;
        h8v ahi = *(const h8v*)pa;
        h8v alo = *(const h8v*)(pa + 64);
#pragma unroll
        for (int nf = 0; nf < 4; ++nf) {
          acc[mf][nf] = __builtin_amdgcn_mfma_f32_16x16x32_f16(ahi, bhi[nf], acc[mf][nf], 0, 0, 0);
          acc[mf][nf] = __builtin_amdgcn_mfma_f32_16x16x32_f16(ahi, blo[nf], acc[mf][nf], 0, 0, 0);
          acc[mf][nf] = __builtin_amdgcn_mfma_f32_16x16x32_f16(alo, bhi[nf], acc[mf][nf], 0, 0, 0);
        }
      }
      item_bot();
    }
    // epilogue: all waves past reads of old h (last item's barrier) -> write
    const float* bh = (const float*)(smb + 512) + L * 128 + mr * 64;
#pragma unroll
    for (int mf = 0; mf < 4; ++mf) {
      f4v bi = *(const f4v*)(bh + mf * 16 + g * 4);
#pragma unroll
      for (int nf = 0; nf < 4; ++nf) {
        f4v v = acc[mf][nf] + bi;
        v[0] = fmaxf(v[0], 0.f); v[1] = fmaxf(v[1], 0.f);
        v[2] = fmaxf(v[2], 0.f); v[3] = fmaxf(v[3], 0.f);
        char* hrow = smh + (nc * 64 + nf * 16 + l15) * HROW;
        split_store(v, hrow + mr * 128 + mf * 32 + g * 8,
                    hrow + 256 + mr * 128 + mf * 32 + g * 8);
        acc[mf][nf] = z;
      }
    }
    asm volatile("s_waitcnt lgkmcnt(0)" ::: "memory");
    __builtin_amdgcn_s_barrier();
    asm volatile("" ::: "memory");
  };

  auto wstage = [&](f4v (&o)[4], int st, int shift) {
    item_top();
    const char* wb = smw + cur * CHUNK;
    if (mr == 0) {  // waves 0,1: wave-uniform branch
      f4v oa[4] = {z, z, z, z};
#pragma unroll
      for (int ss = 0; ss < 4; ++ss) {
        const char* pa = wb + l15 * HROW + ss * 64 + g * 16;
        h8v ahi = *(const h8v*)pa;
        h8v alo = *(const h8v*)(pa + 256);
#pragma unroll
        for (int nf = 0; nf < 4; ++nf) {
          const char* pb = smh + (nc * 64 + nf * 16 + l15) * HROW + ss * 64 + g * 16;
          h8v bhi = *(const h8v*)pb;
          h8v blo = *(const h8v*)(pb + 256);
          oa[nf] = __builtin_amdgcn_mfma_f32_16x16x32_f16(ahi, bhi, oa[nf], 0, 0, 0);
          oa[nf] = __builtin_amdgcn_mfma_f32_16x16x32_f16(ahi, blo, oa[nf], 0, 0, 0);
          oa[nf] = __builtin_amdgcn_mfma_f32_16x16x32_f16(alo, bhi, oa[nf], 0, 0, 0);
        }
      }
      f4v bi = *(const f4v*)((const float*)(smb + 7680) + st * 16 + g * 4);
#pragma unroll
      for (int nf = 0; nf < 4; ++nf) {
        oa[nf] += bi;  // padded classes carry bias -1e30
        float m = fmaxf(fmaxf(oa[nf][0], oa[nf][1]), fmaxf(oa[nf][2], oa[nf][3]));
        m = fmaxf(m, __shfl_xor(m, 16, 64));
        m = fmaxf(m, __shfl_xor(m, 32, 64));
        if (m > 0.5f) conf |= 1u << (shift + nf);
        o[nf] = oa[nf];
      }
    }
    item_bot();
  };

#pragma unroll 1
  for (int L = 0; L < 4; ++L) hidden(L);
  wstage(o0, 0, 0);
#pragma unroll 1
  for (int L = 4; L < 9; ++L) hidden(L);
  wstage(o1, 1, 4);
#pragma unroll 1
  for (int L = 9; L < 14; ++L) hidden(L);
  wstage(o2, 2, 8);

  if (mr == 0) {  // early-exit select + store
#pragma unroll
    for (int nf = 0; nf < 4; ++nf) {
      bool c0 = (conf >> nf) & 1u, c1 = (conf >> (4 + nf)) & 1u;
      f4v r;
#pragma unroll
      for (int j = 0; j < 4; ++j) r[j] = c0 ? o0[nf][j] : (c1 ? o1[nf][j] : o2[nf][j]);
      float* dp = out + (size_t)(tile * 128 + nc * 64 + nf * 16 + l15) * 10;
      if (g == 0) {
        *(float2*)(dp) = make_float2(r[0], r[1]);
        *(float2*)(dp + 2) = make_float2(r[2], r[3]);
      } else if (g == 1) {
        *(float2*)(dp + 4) = make_float2(r[0], r[1]);
        *(float2*)(dp + 6) = make_float2(r[2], r[3]);
      } else if (g == 2) {
        *(float2*)(dp + 8) = make_float2(r[0], r[1]);
      }
    }
  }
}

// ---------------------------------------------------------------------------
extern "C" void kernel_launch(void* const* d_in, const int* in_sizes, int n_in,
                              void* d_out, int out_size, void* d_ws, size_t ws_size,
                              hipStream_t stream) {
  (void)in_sizes; (void)n_in; (void)out_size; (void)ws_size;
  const float* x     = (const float*)d_in[0];
  const float* w_in  = (const float*)d_in[1];
  const float* b_in  = (const float*)d_in[2];
  const float* w_hid = (const float*)d_in[3];
  const float* b_hid = (const float*)d_in[4];
  const float* w_out = (const float*)d_in[5];
  const float* b_out = (const float*)d_in[6];
  float* out = (float*)d_out;
  char* ws = (char*)d_ws;

  (void)hipFuncSetAttribute((const void*)fused_k,
                            hipFuncAttributeMaxDynamicSharedMemorySize, SMEM_BYTES);

  prep_k<<<315, 256, 0, stream>>>(w_in, b_in, w_hid, b_hid, w_out, b_out, ws);
  fused_k<<<512, 256, SMEM_BYTES, stream>>>(x, ws, out);
}

// Round 7
// 358.656 us; speedup vs baseline: 1.3998x; 1.0520x over previous
//
#include <hip/hip_runtime.h>

// ---------------------------------------------------------------------------
// Cascade MLP, MI355X. fp16 hi/lo split GEMMs on MFMA (3 passes, fp32 accum).
// k-OCTET mapping: lane (l15,g) holds k in [8g,8g+8) for A and B. Rows store
// [hi-plane][lo-plane] -> one fragment == one ds_read_b128. Fused; h in LDS.
// Round-7: (1) phase-1 BK=64 (2 chunks/step, 48 steps -> half the barriers,
// 96 MFMA/wave per barrier); (2) phase-2 safe ring: wait vmcnt(5) -> barrier
// -> stage(i+2) -> compute(i), 4 bufs (stage only writes a buffer whose
// readers finished >=2 barriers ago -- fixes the r6 ordering race);
// (3) biases via FIFO-disciplined global loads (issued 2 rings early).
// ---------------------------------------------------------------------------

typedef __fp16 h2  __attribute__((ext_vector_type(2)));
typedef __fp16 h8v __attribute__((ext_vector_type(8)));
typedef float  f4v __attribute__((ext_vector_type(4)));

#define CHUNK 20480   // W chunk stride (18432 used: 128 rows x 144 B), 5x16B stage
#define WROW  144     // weight row: [hi 64B][lo 64B][pad 16B]
#define HROW  528     // h row: [hi 256B][lo 256B][pad 16B]
#define WOCH  20480   // head chunk stride (8448 used: 16 rows x 528 B)

static constexpr unsigned OFF_W1  = 0;                       // 96 chunks
static constexpr unsigned OFF_WH  = 96u * CHUNK;             // 56 chunks
static constexpr unsigned OFF_WO  = OFF_WH + 56u * CHUNK;    // 3 head chunks
static constexpr unsigned OFF_BIN = OFF_WO + 3u * WOCH;      // 128 f32
static constexpr unsigned OFF_BH  = OFF_BIN + 512;           // 14 x 128 f32
static constexpr unsigned OFF_BO  = OFF_BH + 7168;           // 3 x 16 f32

#define LDS_W 67584                      // h: 128*528
#define SMEM_BYTES (67584 + 4 * CHUNK)   // + 81920 = 149504

__device__ __forceinline__ unsigned bc2(h2 v) { return __builtin_bit_cast(unsigned, v); }

__device__ __forceinline__ f4v ntld4(const float* p) {
  return __builtin_nontemporal_load((const f4v*)p);
}

__device__ __forceinline__ void lds_cp16(const char* g, char* l) {
  __builtin_amdgcn_global_load_lds(
      (const __attribute__((address_space(1))) void*)g,
      (__attribute__((address_space(3))) void*)l, 16, 0, 0);
}

__device__ __forceinline__ void stage5(const char* g, char* l, int tid) {
#pragma unroll
  for (int i = 0; i < 5; ++i) lds_cp16(g + i * 4096 + tid * 16, l + i * 4096 + tid * 16);
}

__device__ __forceinline__ void cvt8(f4v a, f4v b, h8v& hi, h8v& lo) {
  h2 h0 = __builtin_amdgcn_cvt_pkrtz(a[0], a[1]);
  h2 h1 = __builtin_amdgcn_cvt_pkrtz(a[2], a[3]);
  h2 h2_ = __builtin_amdgcn_cvt_pkrtz(b[0], b[1]);
  h2 h3 = __builtin_amdgcn_cvt_pkrtz(b[2], b[3]);
  h2 l0 = __builtin_amdgcn_cvt_pkrtz(a[0] - (float)h0[0], a[1] - (float)h0[1]);
  h2 l1 = __builtin_amdgcn_cvt_pkrtz(a[2] - (float)h1[0], a[3] - (float)h1[1]);
  h2 l2 = __builtin_amdgcn_cvt_pkrtz(b[0] - (float)h2_[0], b[1] - (float)h2_[1]);
  h2 l3 = __builtin_amdgcn_cvt_pkrtz(b[2] - (float)h3[0], b[3] - (float)h3[1]);
  hi = h8v{h0[0], h0[1], h1[0], h1[1], h2_[0], h2_[1], h3[0], h3[1]};
  lo = h8v{l0[0], l0[1], l1[0], l1[1], l2[0], l2[1], l3[0], l3[1]};
}

__device__ __forceinline__ void split_store(f4v v, char* hip, char* lop) {
  h2 a = __builtin_amdgcn_cvt_pkrtz(v[0], v[1]);
  h2 b = __builtin_amdgcn_cvt_pkrtz(v[2], v[3]);
  h2 c = __builtin_amdgcn_cvt_pkrtz(v[0] - (float)a[0], v[1] - (float)a[1]);
  h2 d = __builtin_amdgcn_cvt_pkrtz(v[2] - (float)b[0], v[3] - (float)b[1]);
  *(uint2*)hip = make_uint2(bc2(a), bc2(b));
  *(uint2*)lop = make_uint2(bc2(c), bc2(d));
}

__device__ __forceinline__ void split8w(const float* f, uint4& hi, uint4& lo) {
  h2 h0 = __builtin_amdgcn_cvt_pkrtz(f[0], f[1]);
  h2 h1 = __builtin_amdgcn_cvt_pkrtz(f[2], f[3]);
  h2 h2_ = __builtin_amdgcn_cvt_pkrtz(f[4], f[5]);
  h2 h3 = __builtin_amdgcn_cvt_pkrtz(f[6], f[7]);
  h2 l0 = __builtin_amdgcn_cvt_pkrtz(f[0] - (float)h0[0], f[1] - (float)h0[1]);
  h2 l1 = __builtin_amdgcn_cvt_pkrtz(f[2] - (float)h1[0], f[3] - (float)h1[1]);
  h2 l2 = __builtin_amdgcn_cvt_pkrtz(f[4] - (float)h2_[0], f[5] - (float)h2_[1]);
  h2 l3 = __builtin_amdgcn_cvt_pkrtz(f[6] - (float)h3[0], f[7] - (float)h3[1]);
  hi = make_uint4(bc2(h0), bc2(h1), bc2(h2_), bc2(h3));
  lo = make_uint4(bc2(l0), bc2(l1), bc2(l2), bc2(l3));
}

// flat items: L0-3=0..15, head0=16, L4-8=17..36, head1=37, L9-13=38..57, head2=58
__device__ __forceinline__ unsigned item_off(int it) {
  if (it >= 58) return OFF_WO + 2u * WOCH;   // 58 + dummy tails
  if (it == 16) return OFF_WO;
  if (it == 37) return OFF_WO + WOCH;
  int j = it - (it > 16 ? 1 : 0) - (it > 37 ? 1 : 0);
  return OFF_WH + (unsigned)j * CHUNK;
}

// ---------------------------------------------------------------------------
__global__ __launch_bounds__(256) void prep_k(
    const float* __restrict__ w_in, const float* __restrict__ b_in,
    const float* __restrict__ w_hid, const float* __restrict__ b_hid,
    const float* __restrict__ w_out, const float* __restrict__ b_out,
    char* __restrict__ ws) {
  int idx = blockIdx.x * 256 + threadIdx.x;
  float f[8];
  uint4 hi, lo;
  if (idx < 49152) {  // W1: c(96) x q(4) x n(128); k = c*32 + q*8 + j
    int n = idx & 127, cq = idx >> 7, q = cq & 3, c = cq >> 2;
    int k0 = c * 32 + q * 8;
#pragma unroll
    for (int j = 0; j < 8; ++j) f[j] = (n < 100) ? w_in[(size_t)(k0 + j) * 100 + n] : 0.f;
    split8w(f, hi, lo);
    char* dst = ws + OFF_W1 + (size_t)c * CHUNK + n * WROW + q * 16;
    *(uint4*)dst = hi;
    *(uint4*)(dst + 64) = lo;
    return;
  }
  idx -= 49152;
  if (idx < 28672) {  // WH: ch(56) x q(4) x n(128); k = s*32 + q*8 + j
    int n = idx & 127, cq = idx >> 7, q = cq & 3, ch = cq >> 2;
    int L = ch >> 2, s = ch & 3;
    int k0 = s * 32 + q * 8;
#pragma unroll
    for (int j = 0; j < 8; ++j) {
      int k = k0 + j;
      f[j] = (k < 100 && n < 100) ? w_hid[(size_t)L * 10000 + k * 100 + n] : 0.f;
    }
    split8w(f, hi, lo);
    char* dst = ws + OFF_WH + (size_t)ch * CHUNK + n * WROW + q * 16;
    *(uint4*)dst = hi;
    *(uint4*)(dst + 64) = lo;
    return;
  }
  idx -= 28672;
  if (idx < 768) {  // WO: st(3) x q(16) x l(16); HROW rows, full 128-k planes
    int l = idx & 15, sq = idx >> 4, q = sq & 15, st = sq >> 4;
    int k0 = q * 8;
#pragma unroll
    for (int j = 0; j < 8; ++j) {
      int k = k0 + j;
      f[j] = (k < 100 && l < 10) ? w_out[(size_t)st * 1000 + k * 10 + l] : 0.f;
    }
    split8w(f, hi, lo);
    char* dst = ws + OFF_WO + (size_t)st * WOCH + l * HROW + q * 16;
    *(uint4*)dst = hi;
    *(uint4*)(dst + 256) = lo;
    return;
  }
  idx -= 768;
  if (idx < 128) { ((float*)(ws + OFF_BIN))[idx] = (idx < 100) ? b_in[idx] : 0.f; return; }
  idx -= 128;
  if (idx < 1792) {
    int L = idx >> 7, n = idx & 127;
    ((float*)(ws + OFF_BH))[idx] = (n < 100) ? b_hid[L * 100 + n] : 0.f;
    return;
  }
  idx -= 1792;
  if (idx < 48) {
    int st = idx >> 4, n = idx & 15;
    ((float*)(ws + OFF_BO))[idx] = (n < 10) ? b_out[st * 10 + n] : -1e30f;
    return;
  }
}

// ---------------------------------------------------------------------------
__global__ __launch_bounds__(256, 1) void fused_k(const float* __restrict__ x,
                                                  char* __restrict__ ws,
                                                  float* __restrict__ out) {
  extern __shared__ __align__(16) char sm[];
  char* smh = sm;            // h tile
  char* smw = sm + LDS_W;    // 4 chunk buffers

  const int tid = threadIdx.x;
  const int lane = tid & 63, wid = tid >> 6;
  const int l15 = lane & 15, g = lane >> 4;
  const int tile = blockIdx.x;

  f4v z = {0.f, 0.f, 0.f, 0.f};

  // ================= phase 1: h = relu(x @ w_in + b_in), BK=64 ============
  {
    const char* w1g = ws + OFF_W1;
    const float* xr0 = x + (size_t)(tile * 128 + wid * 32 + l15) * 3072;
    const float* xr1 = xr0 + (size_t)16 * 3072;

    f4v xaP[8], xaQ[8];
    // prologue FIFO: cc0(10), x0(8), x1(8)
    stage5(w1g, smw, tid);
    stage5(w1g + CHUNK, smw + CHUNK, tid);
    __builtin_amdgcn_sched_barrier(0);
    {
      const int o = g * 8;
      xaP[0] = ntld4(xr0 + o);      xaP[1] = ntld4(xr0 + o + 4);
      xaP[2] = ntld4(xr0 + o + 32); xaP[3] = ntld4(xr0 + o + 36);
      xaP[4] = ntld4(xr1 + o);      xaP[5] = ntld4(xr1 + o + 4);
      xaP[6] = ntld4(xr1 + o + 32); xaP[7] = ntld4(xr1 + o + 36);
    }
    __builtin_amdgcn_sched_barrier(0);
    {
      const int o = 64 + g * 8;
      xaQ[0] = ntld4(xr0 + o);      xaQ[1] = ntld4(xr0 + o + 4);
      xaQ[2] = ntld4(xr0 + o + 32); xaQ[3] = ntld4(xr0 + o + 36);
      xaQ[4] = ntld4(xr1 + o);      xaQ[5] = ntld4(xr1 + o + 4);
      xaQ[6] = ntld4(xr1 + o + 32); xaQ[7] = ntld4(xr1 + o + 36);
    }
    __builtin_amdgcn_sched_barrier(0);

    f4v acc[8][2];
#pragma unroll
    for (int mf = 0; mf < 8; ++mf) { acc[mf][0] = z; acc[mf][1] = z; }

    const int abase = l15 * WROW + g * 16;

    auto step = [&](int s, f4v (&xa)[8]) {
      if (s == 47) asm volatile("s_waitcnt vmcnt(0)" ::: "memory");
      else         asm volatile("s_waitcnt vmcnt(8)" ::: "memory");
      __builtin_amdgcn_s_barrier();
      asm volatile("" ::: "memory");

      h8v b0Ah, b0Al, b0Bh, b0Bl, b1Ah, b1Al, b1Bh, b1Bl;
      cvt8(xa[0], xa[1], b0Ah, b0Al);
      cvt8(xa[2], xa[3], b0Bh, b0Bl);
      cvt8(xa[4], xa[5], b1Ah, b1Al);
      cvt8(xa[6], xa[7], b1Bh, b1Bl);
      if (s + 1 < 48) {  // stage chunk pair (s+1) into the other buf pair
        char* dst = smw + ((s + 1) & 1) * 2 * CHUNK;
        stage5(w1g + (size_t)(2 * s + 2) * CHUNK, dst, tid);
        stage5(w1g + (size_t)(2 * s + 3) * CHUNK, dst + CHUNK, tid);
      }
      if (s + 2 < 48) {
        const int o = (s + 2) * 64 + g * 8;
        xa[0] = ntld4(xr0 + o);      xa[1] = ntld4(xr0 + o + 4);
        xa[2] = ntld4(xr0 + o + 32); xa[3] = ntld4(xr0 + o + 36);
        xa[4] = ntld4(xr1 + o);      xa[5] = ntld4(xr1 + o + 4);
        xa[6] = ntld4(xr1 + o + 32); xa[7] = ntld4(xr1 + o + 36);
      }
      __builtin_amdgcn_sched_barrier(0);

      const char* ab = smw + (s & 1) * 2 * CHUNK + abase;
#pragma unroll
      for (int mf = 0; mf < 8; ++mf) {
        const char* pa = ab + mf * (16 * WROW);
        h8v ahiA = *(const h8v*)pa;
        h8v aloA = *(const h8v*)(pa + 64);
        h8v ahiB = *(const h8v*)(pa + CHUNK);
        h8v aloB = *(const h8v*)(pa + CHUNK + 64);
        acc[mf][0] = __builtin_amdgcn_mfma_f32_16x16x32_f16(ahiA, b0Ah, acc[mf][0], 0, 0, 0);
        acc[mf][0] = __builtin_amdgcn_mfma_f32_16x16x32_f16(ahiA, b0Al, acc[mf][0], 0, 0, 0);
        acc[mf][0] = __builtin_amdgcn_mfma_f32_16x16x32_f16(aloA, b0Ah, acc[mf][0], 0, 0, 0);
        acc[mf][0] = __builtin_amdgcn_mfma_f32_16x16x32_f16(ahiB, b0Bh, acc[mf][0], 0, 0, 0);
        acc[mf][0] = __builtin_amdgcn_mfma_f32_16x16x32_f16(ahiB, b0Bl, acc[mf][0], 0, 0, 0);
        acc[mf][0] = __builtin_amdgcn_mfma_f32_16x16x32_f16(aloB, b0Bh, acc[mf][0], 0, 0, 0);
        acc[mf][1] = __builtin_amdgcn_mfma_f32_16x16x32_f16(ahiA, b1Ah, acc[mf][1], 0, 0, 0);
        acc[mf][1] = __builtin_amdgcn_mfma_f32_16x16x32_f16(ahiA, b1Al, acc[mf][1], 0, 0, 0);
        acc[mf][1] = __builtin_amdgcn_mfma_f32_16x16x32_f16(aloA, b1Ah, acc[mf][1], 0, 0, 0);
        acc[mf][1] = __builtin_amdgcn_mfma_f32_16x16x32_f16(ahiB, b1Bh, acc[mf][1], 0, 0, 0);
        acc[mf][1] = __builtin_amdgcn_mfma_f32_16x16x32_f16(ahiB, b1Bl, acc[mf][1], 0, 0, 0);
        acc[mf][1] = __builtin_amdgcn_mfma_f32_16x16x32_f16(aloB, b1Bh, acc[mf][1], 0, 0, 0);
      }
    };

#pragma unroll 1
    for (int s2 = 0; s2 < 48; s2 += 2) {
      step(s2, xaP);
      step(s2 + 1, xaQ);
    }

    // epilogue: bias (global, FIFO-front), pre-stage items 0,1, write h
    f4v bin[8];
    {
      const float* bp = (const float*)(ws + OFF_BIN) + g * 4;
#pragma unroll
      for (int mf = 0; mf < 8; ++mf) bin[mf] = *(const f4v*)(bp + mf * 16);
    }
    __builtin_amdgcn_sched_barrier(0);
    stage5(ws + item_off(0), smw, tid);
    stage5(ws + item_off(1), smw + CHUNK, tid);
    asm volatile("s_waitcnt vmcnt(10)" ::: "memory");  // bias done, items in flight
#pragma unroll
    for (int nf = 0; nf < 2; ++nf) {
      char* hrow = smh + (wid * 32 + nf * 16 + l15) * HROW;
#pragma unroll
      for (int mf = 0; mf < 8; ++mf) {
        f4v v = acc[mf][nf] + bin[mf];
        v[0] = fmaxf(v[0], 0.f); v[1] = fmaxf(v[1], 0.f);
        v[2] = fmaxf(v[2], 0.f); v[3] = fmaxf(v[3], 0.f);
        split_store(v, hrow + mf * 32 + g * 8, hrow + 256 + mf * 32 + g * 8);
      }
    }
    asm volatile("s_waitcnt lgkmcnt(0)" ::: "memory");
    __builtin_amdgcn_s_barrier();
    asm volatile("" ::: "memory");
  }

  // ================= phase 2: cascade, safe 4-buf ring =====================
  const int mr = wid >> 1, nc = wid & 1;
  f4v acc2[4][4] = {{z, z, z, z}, {z, z, z, z}, {z, z, z, z}, {z, z, z, z}};
  f4v o0[4], o1[4], o2[4];
  f4v bh[4], bo = z;
  unsigned conf = 0;

  // ring: wait(stage(i) done) -> barrier -> stage(i+2) -> compute(i)
  auto ring_top = [&](int i) {
    asm volatile("s_waitcnt vmcnt(5)" ::: "memory");
    __builtin_amdgcn_s_barrier();
    asm volatile("" ::: "memory");
    stage5(ws + item_off(i + 2), smw + ((i + 2) & 3) * CHUNK, tid);
  };

  auto hidden = [&](int base, int L, bool headNext, int stNext) {
#pragma unroll
    for (int ss = 0; ss < 4; ++ss) {
      ring_top(base + ss);
      if (ss == 1) {  // layer bias, confirmed by ring(base+3)'s wait
        const float* bp = (const float*)(ws + OFF_BH) + L * 128 + mr * 64 + g * 4;
#pragma unroll
        for (int mf = 0; mf < 4; ++mf) bh[mf] = *(const f4v*)(bp + mf * 16);
      }
      if (ss == 2 && headNext)  // head bias, confirmed 2 rings later
        bo = *(const f4v*)((const float*)(ws + OFF_BO) + stNext * 16 + g * 4);
      const char* wb = smw + ((base + ss) & 3) * CHUNK + g * 16;
      const char* hb = smh + ss * 64 + g * 16;
      h8v bhi[4], blo[4];
#pragma unroll
      for (int nf = 0; nf < 4; ++nf) {
        const char* p = hb + (nc * 64 + nf * 16 + l15) * HROW;
        bhi[nf] = *(const h8v*)p;
        blo[nf] = *(const h8v*)(p + 256);
      }
#pragma unroll
      for (int mf = 0; mf < 4; ++mf) {
        const char* pa = wb + (mr * 64 + mf * 16 + l15) * WROW;
        h8v ahi = *(const h8v*)pa;
        h8v alo = *(const h8v*)(pa + 64);
#pragma unroll
        for (int nf = 0; nf < 4; ++nf) {
          acc2[mf][nf] = __builtin_amdgcn_mfma_f32_16x16x32_f16(ahi, bhi[nf], acc2[mf][nf], 0, 0, 0);
          acc2[mf][nf] = __builtin_amdgcn_mfma_f32_16x16x32_f16(ahi, blo[nf], acc2[mf][nf], 0, 0, 0);
          acc2[mf][nf] = __builtin_amdgcn_mfma_f32_16x16x32_f16(alo, bhi[nf], acc2[mf][nf], 0, 0, 0);
        }
      }
    }
    // epilogue: all waves done reading old h -> overwrite
    __builtin_amdgcn_s_barrier();
    asm volatile("" ::: "memory");
#pragma unroll
    for (int mf = 0; mf < 4; ++mf) {
#pragma unroll
      for (int nf = 0; nf < 4; ++nf) {
        f4v v = acc2[mf][nf] + bh[mf];
        v[0] = fmaxf(v[0], 0.f); v[1] = fmaxf(v[1], 0.f);
        v[2] = fmaxf(v[2], 0.f); v[3] = fmaxf(v[3], 0.f);
        char* hrow = smh + (nc * 64 + nf * 16 + l15) * HROW;
        split_store(v, hrow + mr * 128 + mf * 32 + g * 8,
                    hrow + 256 + mr * 128 + mf * 32 + g * 8);
        acc2[mf][nf] = z;
      }
    }
    asm volatile("s_waitcnt lgkmcnt(0)" ::: "memory");
    __builtin_amdgcn_s_barrier();
    asm volatile("" ::: "memory");
  };

  auto wstage = [&](int i, f4v (&o)[4], int shift) {
    ring_top(i);
    const char* wb = smw + (i & 3) * CHUNK;
    if (mr == 0) {  // waves 0,1: wave-uniform branch
      f4v oa[4] = {z, z, z, z};
#pragma unroll
      for (int ss = 0; ss < 4; ++ss) {
        const char* pa = wb + l15 * HROW + ss * 64 + g * 16;
        h8v ahi = *(const h8v*)pa;
        h8v alo = *(const h8v*)(pa + 256);
#pragma unroll
        for (int nf = 0; nf < 4; ++nf) {
          const char* pb = smh + (nc * 64 + nf * 16 + l15) * HROW + ss * 64 + g * 16;
          h8v bhi = *(const h8v*)pb;
          h8v blo = *(const h8v*)(pb + 256);
          oa[nf] = __builtin_amdgcn_mfma_f32_16x16x32_f16(ahi, bhi, oa[nf], 0, 0, 0);
          oa[nf] = __builtin_amdgcn_mfma_f32_16x16x32_f16(ahi, blo, oa[nf], 0, 0, 0);
          oa[nf] = __builtin_amdgcn_mfma_f32_16x16x32_f16(alo, bhi, oa[nf], 0, 0, 0);
        }
      }
#pragma unroll
      for (int nf = 0; nf < 4; ++nf) {
        oa[nf] += bo;  // padded classes carry bias -1e30
        float m = fmaxf(fmaxf(oa[nf][0], oa[nf][1]), fmaxf(oa[nf][2], oa[nf][3]));
        m = fmaxf(m, __shfl_xor(m, 16, 64));
        m = fmaxf(m, __shfl_xor(m, 32, 64));
        if (m > 0.5f) conf |= 1u << (shift + nf);
        o[nf] = oa[nf];
      }
    }
  };

  hidden(0, 0, false, 0);
  hidden(4, 1, false, 0);
  hidden(8, 2, false, 0);
  hidden(12, 3, true, 0);
  wstage(16, o0, 0);
  hidden(17, 4, false, 0);
  hidden(21, 5, false, 0);
  hidden(25, 6, false, 0);
  hidden(29, 7, false, 0);
  hidden(33, 8, true, 1);
  wstage(37, o1, 4);
  hidden(38, 9, false, 0);
  hidden(42, 10, false, 0);
  hidden(46, 11, false, 0);
  hidden(50, 12, false, 0);
  hidden(54, 13, true, 2);
  wstage(58, o2, 8);

  if (mr == 0) {  // early-exit select + store
#pragma unroll
    for (int nf = 0; nf < 4; ++nf) {
      bool c0 = (conf >> nf) & 1u, c1 = (conf >> (4 + nf)) & 1u;
      f4v r;
#pragma unroll
      for (int j = 0; j < 4; ++j) r[j] = c0 ? o0[nf][j] : (c1 ? o1[nf][j] : o2[nf][j]);
      float* dp = out + (size_t)(tile * 128 + nc * 64 + nf * 16 + l15) * 10;
      if (g == 0) {
        *(float2*)(dp) = make_float2(r[0], r[1]);
        *(float2*)(dp + 2) = make_float2(r[2], r[3]);
      } else if (g == 1) {
        *(float2*)(dp + 4) = make_float2(r[0], r[1]);
        *(float2*)(dp + 6) = make_float2(r[2], r[3]);
      } else if (g == 2) {
        *(float2*)(dp + 8) = make_float2(r[0], r[1]);
      }
    }
  }
}

// ---------------------------------------------------------------------------
extern "C" void kernel_launch(void* const* d_in, const int* in_sizes, int n_in,
                              void* d_out, int out_size, void* d_ws, size_t ws_size,
                              hipStream_t stream) {
  (void)in_sizes; (void)n_in; (void)out_size; (void)ws_size;
  const float* x     = (const float*)d_in[0];
  const float* w_in  = (const float*)d_in[1];
  const float* b_in  = (const float*)d_in[2];
  const float* w_hid = (const float*)d_in[3];
  const float* b_hid = (const float*)d_in[4];
  const float* w_out = (const float*)d_in[5];
  const float* b_out = (const float*)d_in[6];
  float* out = (float*)d_out;
  char* ws = (char*)d_ws;

  (void)hipFuncSetAttribute((const void*)fused_k,
                            hipFuncAttributeMaxDynamicSharedMemorySize, SMEM_BYTES);

  prep_k<<<315, 256, 0, stream>>>(w_in, b_in, w_hid, b_hid, w_out, b_out, ws);
  fused_k<<<512, 256, SMEM_BYTES, stream>>>(x, ws, out);
}